// Round 4
// baseline (170.733 us; speedup 1.0000x reference)
//
#include <hip/hip_runtime.h>
#include <stdint.h>

typedef unsigned short u16;
typedef __attribute__((ext_vector_type(8))) short bf16x8;
typedef __attribute__((ext_vector_type(4))) float f32x4;

#define NTOK 1024      // H*W
#define DMODEL 256
#define NHEAD 8
#define DK 32
#define NBATCH 8
#define PER_B (DMODEL * NTOK)   // 262144

__device__ __forceinline__ float b2f(u16 h) {
    union { unsigned u; float f; } c; c.u = ((unsigned)h) << 16; return c.f;
}
__device__ __forceinline__ u16 f2b(float f) {
    unsigned u = __float_as_uint(f);
    unsigned r = u + 0x7fffu + ((u >> 16) & 1u);
    return (u16)(r >> 16);
}

// ---------------- Kernel 1: fused weight-convert + LN partial sums ----------------
// blocks 0..255: cvt (4 matrices x 64 blocks); blocks 256..319: ln partials (8 b x 8 slices)
__global__ void prep(const float* __restrict__ Wq, const float* __restrict__ Wk,
                     const float* __restrict__ Wv, const float* __restrict__ Wo,
                     u16* __restrict__ wb,
                     const float* __restrict__ x, float* __restrict__ part) {
    int bx = blockIdx.x;
    int t = threadIdx.x;
    if (bx < 256) {
        int m = bx >> 6;
        const float* W = (m == 0) ? Wq : (m == 1) ? Wk : (m == 2) ? Wv : Wo;
        int i = ((bx & 63) * 256 + t) * 4;
        float4 v = *(const float4*)&W[i];
        ushort4 o;
        o.x = f2b(v.x); o.y = f2b(v.y); o.z = f2b(v.z); o.w = f2b(v.w);
        *(ushort4*)&wb[m * 65536 + i] = o;
        return;
    }
    int blk = bx - 256;
    int b = blk >> 3, sl = blk & 7;
    int w = t >> 6, l = t & 63;
    const float* xb = x + (size_t)b * PER_B + sl * (PER_B / 8);
    float s = 0.f, ss = 0.f;
    for (int base = 0; base < PER_B / 8; base += 1024) {
        float4 v = *(const float4*)&xb[base + t * 4];
        s += v.x + v.y + v.z + v.w;
        ss += v.x * v.x + v.y * v.y + v.z * v.z + v.w * v.w;
    }
    for (int d = 1; d < 64; d <<= 1) {
        s += __shfl_xor(s, d, 64);
        ss += __shfl_xor(ss, d, 64);
    }
    __shared__ float red[2][4];
    if (l == 0) { red[0][w] = s; red[1][w] = ss; }
    __syncthreads();
    if (t == 0) {
        float S = red[0][0] + red[0][1] + red[0][2] + red[0][3];
        float SS = red[1][0] + red[1][1] + red[1][2] + red[1][3];
        part[(b * 8 + sl) * 2] = S;
        part[(b * 8 + sl) * 2 + 1] = SS;
    }
}

// ---------------- Kernel 2: normalize + transpose [c,n] -> [n,c], fp32 -> bf16 ----------------
__global__ void normT(const float* __restrict__ x, const float* __restrict__ part,
                      u16* __restrict__ xn) {
    int b = blockIdx.z;
    int n0 = blockIdx.x * 32;
    int c0 = blockIdx.y * 32;
    int tx = threadIdx.x, ty = threadIdx.y;   // (32, 8)
    __shared__ float s_mu, s_rs;
    __shared__ float tile[32][33];
    if (tx == 0 && ty == 0) {
        float S = 0.f, SS = 0.f;
        for (int i = 0; i < 8; ++i) { S += part[(b * 8 + i) * 2]; SS += part[(b * 8 + i) * 2 + 1]; }
        float mu = S / (float)PER_B;
        float var = SS / (float)PER_B - mu * mu;
        s_mu = mu;
        s_rs = rsqrtf(var + 1e-5f);
    }
    __syncthreads();
    float mu = s_mu, rs = s_rs;
    const float* xb = x + (size_t)b * PER_B;
#pragma unroll
    for (int i = 0; i < 4; ++i) {
        int c = c0 + ty + i * 8;
        tile[ty + i * 8][tx] = (xb[c * NTOK + n0 + tx] - mu) * rs;
    }
    __syncthreads();
    u16* xnb = xn + (size_t)b * PER_B;
#pragma unroll
    for (int i = 0; i < 4; ++i) {
        int n = n0 + ty + i * 8;
        xnb[n * DMODEL + c0 + tx] = f2b(tile[tx][ty + i * 8]);
    }
}

// ---------------- Kernel 3: QKV projection, fragment-direct (no LDS, no barriers) ----------------
// grid (64 msub, 24 = sel*8+b); block 256 = 4 waves; wave w computes 16 tokens x 64 outputs
// q,k outputs: [bh][n][32];  v output: TRANSPOSED [bh][dv][n]
__global__ __launch_bounds__(256) void qkv_gemm(
    const u16* __restrict__ xn, const u16* __restrict__ wb,
    const float* __restrict__ bq, const float* __restrict__ bk,
    const float* __restrict__ bv,
    u16* __restrict__ qo, u16* __restrict__ ko, u16* __restrict__ vo) {
    int m0 = blockIdx.x * 16;
    int sel = blockIdx.y >> 3;
    int b = blockIdx.y & 7;
    const u16* W = wb + sel * 65536;
    const float* bias = (sel == 0) ? bq : (sel == 1) ? bk : bv;

    int t = threadIdx.x;
    int w = t >> 6, l = t & 63;
    int qd = l >> 4, ln = l & 15;
    int o0 = w * 64;

    const u16* xb = xn + ((size_t)b * NTOK + m0 + ln) * DMODEL;
    const u16* wB = W + (size_t)(o0 + ln) * DMODEL;

    f32x4 acc[4] = {};
#pragma unroll
    for (int kb = 0; kb < 8; ++kb) {
        bf16x8 af = *(const bf16x8*)&xb[kb * 32 + qd * 8];
        bf16x8 bf0 = *(const bf16x8*)&wB[ 0 * DMODEL + kb * 32 + qd * 8];
        bf16x8 bf1 = *(const bf16x8*)&wB[16 * DMODEL + kb * 32 + qd * 8];
        bf16x8 bf2 = *(const bf16x8*)&wB[32 * DMODEL + kb * 32 + qd * 8];
        bf16x8 bf3 = *(const bf16x8*)&wB[48 * DMODEL + kb * 32 + qd * 8];
        acc[0] = __builtin_amdgcn_mfma_f32_16x16x32_bf16(af, bf0, acc[0], 0, 0, 0);
        acc[1] = __builtin_amdgcn_mfma_f32_16x16x32_bf16(af, bf1, acc[1], 0, 0, 0);
        acc[2] = __builtin_amdgcn_mfma_f32_16x16x32_bf16(af, bf2, acc[2], 0, 0, 0);
        acc[3] = __builtin_amdgcn_mfma_f32_16x16x32_bf16(af, bf3, acc[3], 0, 0, 0);
    }
    if (sel < 2) {
        u16* outp = (sel == 0) ? qo : ko;
        float scale = (sel == 0) ? 0.17677669529663687f : 1.0f;  // DK^-0.5 folded into q
#pragma unroll
        for (int ns = 0; ns < 4; ++ns) {
            int o = o0 + ns * 16 + ln;          // 0..255
            float bias_f = bias[o];
            int head = o >> 5, d = o & 31;
#pragma unroll
            for (int r = 0; r < 4; ++r) {
                int n_row = m0 + qd * 4 + r;
                float v = (acc[ns][r] + bias_f) * scale;
                outp[(((size_t)b * NHEAD + head) * NTOK + n_row) * DK + d] = f2b(v);
            }
        }
    } else {
        int n0 = m0 + qd * 4;
#pragma unroll
        for (int ns = 0; ns < 4; ++ns) {
            int o = o0 + ns * 16 + ln;
            float bias_f = bias[o];
            int head = o >> 5, d = o & 31;
            ushort4 pk;
            pk.x = f2b(acc[ns][0] + bias_f);
            pk.y = f2b(acc[ns][1] + bias_f);
            pk.z = f2b(acc[ns][2] + bias_f);
            pk.w = f2b(acc[ns][3] + bias_f);
            *(ushort4*)&vo[(((size_t)b * NHEAD + head) * DK + d) * NTOK + n0] = pk;
        }
    }
}

// ---------------- Kernel 4: attention, k-split x2, no-max softmax ----------------
// grid (64 bh, 32 qp): bh fastest -> all blocks of a bh land on XCD bh%8 (L2 affinity).
// block 256 = 4 waves: wave = qsub*2 + khalf. Wave: 16 q rows, 512 keys (8 kt of 64).
// Partner waves (khalf 0/1) merge O and l through LDS: pure add (no max tracking).
__global__ __launch_bounds__(256, 8) void attn(
    const u16* __restrict__ qws, const u16* __restrict__ kws,
    const u16* __restrict__ vtws, u16* __restrict__ tmp) {
    int bh = blockIdx.x;
    int qp = blockIdx.y;
    int b = bh >> 3, h = bh & 7;
    const u16* Q  = qws  + (size_t)bh * NTOK * DK;
    const u16* K  = kws  + (size_t)bh * NTOK * DK;
    const u16* Vt = vtws + (size_t)bh * DK * NTOK;   // [dv][n]

    __shared__ u16 Ps[4][16 * 80];       // per-wave P tile (swizzled)
    __shared__ float xch[2][64][13];     // k-half merge: 12 floats/lane, stride 13 (odd)

    int t = threadIdx.x;
    int w = t >> 6, l = t & 63;
    int qsub = w >> 1, khalf = w & 1;
    int qd = l >> 4, ln = l & 15;
    u16* psw = &Ps[w][0];
    int kbase = khalf * 512;

    // Q fragment: rows q = qp*32 + qsub*16 + ln
    bf16x8 qf = *(const bf16x8*)&Q[(qp * 32 + qsub * 16 + ln) * DK + qd * 8];

    // P LDS addressing (loop-invariant), 16B-chunk XOR swizzle -> conflict-free
    int wbase[4];
#pragma unroll
    for (int ns = 0; ns < 4; ++ns)
        wbase[ns] = (qd * 4) * 80 + ((2 * ns + (ln >> 3)) ^ qd) * 8 + (ln & 7);
    const bf16x8* rb[2];
#pragma unroll
    for (int kh = 0; kh < 2; ++kh)
        rb[kh] = (const bf16x8*)&psw[ln * 80 + (((kh * 4 + qd) ^ (ln >> 2)) * 8)];

    float lsum[4] = {0.f, 0.f, 0.f, 0.f};
    f32x4 oacc[2] = {};

    for (int kt = 0; kt < 8; ++kt) {
        int k0 = kbase + kt * 64;
        bf16x8 kf0 = *(const bf16x8*)&K[(k0 +  0 + ln) * DK + qd * 8];
        bf16x8 kf1 = *(const bf16x8*)&K[(k0 + 16 + ln) * DK + qd * 8];
        bf16x8 kf2 = *(const bf16x8*)&K[(k0 + 32 + ln) * DK + qd * 8];
        bf16x8 kf3 = *(const bf16x8*)&K[(k0 + 48 + ln) * DK + qd * 8];
        bf16x8 vf00 = *(const bf16x8*)&Vt[( 0 + ln) * NTOK + k0 +  0 + qd * 8];
        bf16x8 vf01 = *(const bf16x8*)&Vt[( 0 + ln) * NTOK + k0 + 32 + qd * 8];
        bf16x8 vf10 = *(const bf16x8*)&Vt[(16 + ln) * NTOK + k0 +  0 + qd * 8];
        bf16x8 vf11 = *(const bf16x8*)&Vt[(16 + ln) * NTOK + k0 + 32 + qd * 8];

        f32x4 s[4];
        f32x4 z = {0.f, 0.f, 0.f, 0.f};
        s[0] = __builtin_amdgcn_mfma_f32_16x16x32_bf16(qf, kf0, z, 0, 0, 0);
        s[1] = __builtin_amdgcn_mfma_f32_16x16x32_bf16(qf, kf1, z, 0, 0, 0);
        s[2] = __builtin_amdgcn_mfma_f32_16x16x32_bf16(qf, kf2, z, 0, 0, 0);
        s[3] = __builtin_amdgcn_mfma_f32_16x16x32_bf16(qf, kf3, z, 0, 0, 0);

#pragma unroll
        for (int ns = 0; ns < 4; ++ns) {
#pragma unroll
            for (int r = 0; r < 4; ++r) {
                float p = __expf(s[ns][r]);
                lsum[r] += p;
                psw[wbase[ns] + r * 80] = f2b(p);
            }
        }
        bf16x8 pf0 = *rb[0];
        bf16x8 pf1 = *rb[1];
        oacc[0] = __builtin_amdgcn_mfma_f32_16x16x32_bf16(pf0, vf00, oacc[0], 0, 0, 0);
        oacc[0] = __builtin_amdgcn_mfma_f32_16x16x32_bf16(pf1, vf01, oacc[0], 0, 0, 0);
        oacc[1] = __builtin_amdgcn_mfma_f32_16x16x32_bf16(pf0, vf10, oacc[1], 0, 0, 0);
        oacc[1] = __builtin_amdgcn_mfma_f32_16x16x32_bf16(pf1, vf11, oacc[1], 0, 0, 0);
    }

    // merge the two k-halves (no-max softmax: plain adds)
    if (khalf == 1) {
#pragma unroll
        for (int r = 0; r < 4; ++r) xch[qsub][l][r] = lsum[r];
#pragma unroll
        for (int i = 0; i < 4; ++i) {
            xch[qsub][l][4 + i] = oacc[0][i];
            xch[qsub][l][8 + i] = oacc[1][i];
        }
    }
    __syncthreads();
    if (khalf == 0) {
#pragma unroll
        for (int r = 0; r < 4; ++r) lsum[r] += xch[qsub][l][r];
#pragma unroll
        for (int i = 0; i < 4; ++i) {
            oacc[0][i] += xch[qsub][l][4 + i];
            oacc[1][i] += xch[qsub][l][8 + i];
        }
        float linv[4];
#pragma unroll
        for (int r = 0; r < 4; ++r) {
            float s = lsum[r];
            s += __shfl_xor(s, 1, 64);
            s += __shfl_xor(s, 2, 64);
            s += __shfl_xor(s, 4, 64);
            s += __shfl_xor(s, 8, 64);
            linv[r] = 1.0f / s;
        }
#pragma unroll
        for (int ns = 0; ns < 2; ++ns) {
#pragma unroll
            for (int r = 0; r < 4; ++r) {
                int n_row = qp * 32 + qsub * 16 + qd * 4 + r;
                float v = oacc[ns][r] * linv[r];
                tmp[((size_t)b * NTOK + n_row) * DMODEL + h * DK + ns * 16 + ln] = f2b(v);
            }
        }
    }
}

// ---------------- Kernel 5: output projection, fragment-direct + residual (fp32 out) ----------------
// grid (64 msub, 8 b); block 256 = 4 waves; wave w: 16 tokens x 64 outputs
__global__ __launch_bounds__(256) void oproj(
    const u16* __restrict__ tmp, const u16* __restrict__ wb,
    const float* __restrict__ bo, const float* __restrict__ x,
    float* __restrict__ out) {
    int m0 = blockIdx.x * 16;
    int b = blockIdx.y;
    const u16* Wo = wb + 3 * 65536;

    int t = threadIdx.x;
    int w = t >> 6, l = t & 63;
    int qd = l >> 4, ln = l & 15;
    int o0 = w * 64;

    const u16* ab = tmp + ((size_t)b * NTOK + m0 + ln) * DMODEL;
    const u16* wB = Wo + (size_t)(o0 + ln) * DMODEL;

    f32x4 acc[4] = {};
#pragma unroll
    for (int kb = 0; kb < 8; ++kb) {
        bf16x8 af = *(const bf16x8*)&ab[kb * 32 + qd * 8];
        bf16x8 bf0 = *(const bf16x8*)&wB[ 0 * DMODEL + kb * 32 + qd * 8];
        bf16x8 bf1 = *(const bf16x8*)&wB[16 * DMODEL + kb * 32 + qd * 8];
        bf16x8 bf2 = *(const bf16x8*)&wB[32 * DMODEL + kb * 32 + qd * 8];
        bf16x8 bf3 = *(const bf16x8*)&wB[48 * DMODEL + kb * 32 + qd * 8];
        acc[0] = __builtin_amdgcn_mfma_f32_16x16x32_bf16(af, bf0, acc[0], 0, 0, 0);
        acc[1] = __builtin_amdgcn_mfma_f32_16x16x32_bf16(af, bf1, acc[1], 0, 0, 0);
        acc[2] = __builtin_amdgcn_mfma_f32_16x16x32_bf16(af, bf2, acc[2], 0, 0, 0);
        acc[3] = __builtin_amdgcn_mfma_f32_16x16x32_bf16(af, bf3, acc[3], 0, 0, 0);
    }
    const float* xb = x + (size_t)b * PER_B;
    float* ob = out + (size_t)b * PER_B;
#pragma unroll
    for (int ns = 0; ns < 4; ++ns) {
        int o = o0 + ns * 16 + ln;   // 0..255
        float bias_f = bo[o];
#pragma unroll
        for (int r = 0; r < 4; ++r) {
            int n_row = m0 + qd * 4 + r;
            size_t idx = (size_t)n_row * DMODEL + o;
            ob[idx] = acc[ns][r] + bias_f + xb[idx];
        }
    }
}

extern "C" void kernel_launch(void* const* d_in, const int* in_sizes, int n_in,
                              void* d_out, int out_size, void* d_ws, size_t ws_size,
                              hipStream_t stream) {
    const float* x  = (const float*)d_in[0];
    const float* Wq = (const float*)d_in[1];
    const float* bq = (const float*)d_in[2];
    const float* Wk = (const float*)d_in[3];
    const float* bk = (const float*)d_in[4];
    const float* Wv = (const float*)d_in[5];
    const float* bv = (const float*)d_in[6];
    const float* Wo = (const float*)d_in[7];
    const float* bo = (const float*)d_in[8];
    float* out = (float*)d_out;

    char* ws = (char*)d_ws;
    float* part = (float*)ws;                          // 1 KB
    u16* wb  = (u16*)(ws + 1024);                      // 512 KB (4 x 256x256 bf16)
    u16* xn  = (u16*)(ws + 1024 + (512u << 10));       // 4 MB (reused as attn output tmp)
    u16* qws = (u16*)(ws + 1024 + (512u << 10) + (4u << 20));
    u16* kws = (u16*)(ws + 1024 + (512u << 10) + (8u << 20));
    u16* vws = (u16*)(ws + 1024 + (512u << 10) + (12u << 20));  // transposed [bh][dv][n]
    u16* tmp = xn;                                     // xn dead after qkv_gemm

    hipLaunchKernelGGL(prep, dim3(320), dim3(256), 0, stream, Wq, Wk, Wv, Wo, wb, x, part);
    hipLaunchKernelGGL(normT, dim3(32, 8, 8), dim3(32, 8), 0, stream, x, part, xn);
    hipLaunchKernelGGL(qkv_gemm, dim3(64, 24), dim3(256), 0, stream,
                       xn, wb, bq, bk, bv, qws, kws, vws);
    hipLaunchKernelGGL(attn, dim3(64, 32), dim3(256), 0, stream, qws, kws, vws, tmp);
    hipLaunchKernelGGL(oproj, dim3(64, 8), dim3(256), 0, stream, tmp, wb, bo, x, out);
}

// Round 5
// 145.516 us; speedup vs baseline: 1.1733x; 1.1733x over previous
//
#include <hip/hip_runtime.h>
#include <stdint.h>

typedef unsigned short u16;
typedef unsigned int u32;
typedef __attribute__((ext_vector_type(8))) short bf16x8;
typedef __attribute__((ext_vector_type(4))) float f32x4;

#define NTOK 1024      // H*W
#define DMODEL 256
#define NHEAD 8
#define DK 32
#define NBATCH 8
#define PER_B (DMODEL * NTOK)   // 262144

__device__ __forceinline__ float b2f(u16 h) {
    union { unsigned u; float f; } c; c.u = ((unsigned)h) << 16; return c.f;
}
__device__ __forceinline__ u16 f2b(float f) {
    unsigned u = __float_as_uint(f);
    unsigned r = u + 0x7fffu + ((u >> 16) & 1u);
    return (u16)(r >> 16);
}

// ---------------- Kernel 1: fused weight-convert + LN partial sums ----------------
__global__ void prep(const float* __restrict__ Wq, const float* __restrict__ Wk,
                     const float* __restrict__ Wv, const float* __restrict__ Wo,
                     u16* __restrict__ wb,
                     const float* __restrict__ x, float* __restrict__ part) {
    int bx = blockIdx.x;
    int t = threadIdx.x;
    if (bx < 256) {
        int m = bx >> 6;
        const float* W = (m == 0) ? Wq : (m == 1) ? Wk : (m == 2) ? Wv : Wo;
        int i = ((bx & 63) * 256 + t) * 4;
        float4 v = *(const float4*)&W[i];
        ushort4 o;
        o.x = f2b(v.x); o.y = f2b(v.y); o.z = f2b(v.z); o.w = f2b(v.w);
        *(ushort4*)&wb[m * 65536 + i] = o;
        return;
    }
    int blk = bx - 256;
    int b = blk >> 3, sl = blk & 7;
    int w = t >> 6, l = t & 63;
    const float* xb = x + (size_t)b * PER_B + sl * (PER_B / 8);
    float s = 0.f, ss = 0.f;
    for (int base = 0; base < PER_B / 8; base += 1024) {
        float4 v = *(const float4*)&xb[base + t * 4];
        s += v.x + v.y + v.z + v.w;
        ss += v.x * v.x + v.y * v.y + v.z * v.z + v.w * v.w;
    }
    for (int d = 1; d < 64; d <<= 1) {
        s += __shfl_xor(s, d, 64);
        ss += __shfl_xor(ss, d, 64);
    }
    __shared__ float red[2][4];
    if (l == 0) { red[0][w] = s; red[1][w] = ss; }
    __syncthreads();
    if (t == 0) {
        float S = red[0][0] + red[0][1] + red[0][2] + red[0][3];
        float SS = red[1][0] + red[1][1] + red[1][2] + red[1][3];
        part[(b * 8 + sl) * 2] = S;
        part[(b * 8 + sl) * 2 + 1] = SS;
    }
}

// ---------------- Kernel 2: normalize + transpose [c,n] -> [n,c], fp32 -> bf16 ----------------
__global__ void normT(const float* __restrict__ x, const float* __restrict__ part,
                      u16* __restrict__ xn) {
    int b = blockIdx.z;
    int n0 = blockIdx.x * 32;
    int c0 = blockIdx.y * 32;
    int tx = threadIdx.x, ty = threadIdx.y;   // (32, 8)
    __shared__ float s_mu, s_rs;
    __shared__ float tile[32][33];
    if (tx == 0 && ty == 0) {
        float S = 0.f, SS = 0.f;
        for (int i = 0; i < 8; ++i) { S += part[(b * 8 + i) * 2]; SS += part[(b * 8 + i) * 2 + 1]; }
        float mu = S / (float)PER_B;
        float var = SS / (float)PER_B - mu * mu;
        s_mu = mu;
        s_rs = rsqrtf(var + 1e-5f);
    }
    __syncthreads();
    float mu = s_mu, rs = s_rs;
    const float* xb = x + (size_t)b * PER_B;
#pragma unroll
    for (int i = 0; i < 4; ++i) {
        int c = c0 + ty + i * 8;
        tile[ty + i * 8][tx] = (xb[c * NTOK + n0 + tx] - mu) * rs;
    }
    __syncthreads();
    u16* xnb = xn + (size_t)b * PER_B;
#pragma unroll
    for (int i = 0; i < 4; ++i) {
        int n = n0 + ty + i * 8;
        xnb[n * DMODEL + c0 + tx] = f2b(tile[tx][ty + i * 8]);
    }
}

// ---------------- Kernel 3: QKV projection GEMM (LDS-staged, round-3 structure) ----------------
// grid (16 m-tiles, 12 o-tiles, 8 b); q-scale folds DK^-0.5 * log2(e) for attn's exp2 path.
__global__ __launch_bounds__(256) void qkv_gemm(
    const u16* __restrict__ xn, const u16* __restrict__ wb,
    const float* __restrict__ bq, const float* __restrict__ bk,
    const float* __restrict__ bv,
    u16* __restrict__ qo, u16* __restrict__ ko, u16* __restrict__ vo) {
    int mt = blockIdx.x;
    int ot = blockIdx.y;
    int b = blockIdx.z;
    int sel = ot >> 2;            // 0=q 1=k 2=v
    int o0 = (ot & 3) * 64;
    const u16* W = wb + sel * 65536;
    const float* bias = (sel == 0) ? bq : (sel == 1) ? bk : bv;

    __shared__ u16 As[64][40];
    __shared__ u16 Bs[64][40];
    int t = threadIdx.x;
    int w = t >> 6, l = t & 63;
    int lr = t >> 2;
    int lc = (t & 3) * 8;
    int qd = l >> 4, ln = l & 15;

    const u16* xb = xn + ((size_t)b * NTOK + mt * 64) * DMODEL;
    f32x4 acc[4] = {};
    for (int kb = 0; kb < 8; ++kb) {
        *(uint4*)&As[lr][lc] = *(const uint4*)&xb[lr * DMODEL + kb * 32 + lc];
        *(uint4*)&Bs[lr][lc] = *(const uint4*)&W[(o0 + lr) * DMODEL + kb * 32 + lc];
        __syncthreads();
        bf16x8 af = *(const bf16x8*)&As[w * 16 + ln][qd * 8];
#pragma unroll
        for (int ns = 0; ns < 4; ++ns) {
            bf16x8 bf = *(const bf16x8*)&Bs[ns * 16 + ln][qd * 8];
            acc[ns] = __builtin_amdgcn_mfma_f32_16x16x32_bf16(af, bf, acc[ns], 0, 0, 0);
        }
        __syncthreads();
    }
    if (sel < 2) {
        u16* outp = (sel == 0) ? qo : ko;
        // q: DK^-0.5 * log2(e) so attn uses exp2 directly
        float scale = (sel == 0) ? 0.25505654344884634f : 1.0f;
#pragma unroll
        for (int ns = 0; ns < 4; ++ns) {
            int o = o0 + ns * 16 + ln;
            float bias_f = bias[o];
            int head = o >> 5, d = o & 31;
#pragma unroll
            for (int r = 0; r < 4; ++r) {
                int n_row = mt * 64 + w * 16 + qd * 4 + r;
                float v = (acc[ns][r] + bias_f) * scale;
                outp[(((size_t)b * NHEAD + head) * NTOK + n_row) * DK + d] = f2b(v);
            }
        }
    } else {
        // V transposed: vo[bh][dv][n]
        int n0 = mt * 64 + w * 16 + qd * 4;
#pragma unroll
        for (int ns = 0; ns < 4; ++ns) {
            int o = o0 + ns * 16 + ln;
            float bias_f = bias[o];
            int head = o >> 5, d = o & 31;
            ushort4 pk;
            pk.x = f2b(acc[ns][0] + bias_f);
            pk.y = f2b(acc[ns][1] + bias_f);
            pk.z = f2b(acc[ns][2] + bias_f);
            pk.w = f2b(acc[ns][3] + bias_f);
            *(ushort4*)&vo[(((size_t)b * NHEAD + head) * DK + d) * NTOK + n0] = pk;
        }
    }
}

// ---------------- Kernel 4: attention (S^T trick + prefetch + packed-b64 P) ----------------
// grid (64 bh, 32 qp): bh fastest -> XCD L2 affinity. 4 waves = (qsub, khalf); wave: 16 q x 512 keys.
// S^T = mfma(kf, qf): lane holds col q=ln, rows key=qd*4+r -> 4 consecutive keys -> packed b64 P writes.
// P row q: 64 keys in 8 chunks of 16B, chunk XOR ((ln>>2)&1) swizzle: writes & b128 reads conflict-free.
// exp2 (log2e folded into q upstream), truncating bf16 pack via v_perm. K/V fragments prefetched 1 kt ahead.
__global__ __launch_bounds__(256, 4) void attn(
    const u16* __restrict__ qws, const u16* __restrict__ kws,
    const u16* __restrict__ vtws, u16* __restrict__ tmp) {
    int bh = blockIdx.x;
    int qp = blockIdx.y;
    int b = bh >> 3, h = bh & 7;
    const u16* Q  = qws  + (size_t)bh * NTOK * DK;
    const u16* K  = kws  + (size_t)bh * NTOK * DK;
    const u16* Vt = vtws + (size_t)bh * DK * NTOK;   // [dv][n]

    __shared__ u16 Ps[4][16 * 80];   // per-wave P tile, swizzled
    __shared__ float xl[2][64];      // khalf merge: l
    __shared__ float xo[2][64][9];   // khalf merge: oacc (8 + pad)

    int t = threadIdx.x;
    int w = t >> 6, l = t & 63;
    int qsub = w >> 1, khalf = w & 1;
    int qd = l >> 4, ln = l & 15;
    u16* psw = &Ps[w][0];
    int kbase = khalf * 512;
    int sw = (ln >> 2) & 1;          // chunk-XOR swizzle bit

    // Q fragment (B operand): n=q=ln, k=qd*8..+7
    bf16x8 qf = *(const bf16x8*)&Q[(qp * 32 + qsub * 16 + ln) * DK + qd * 8];

    // P write addrs: 4 b64 per kt. key = ns*16 + qd*4 + r at row q=ln.
    // chunk cw = 2ns + (qd>>1), swizzled ^sw, intra-chunk offset 4*(qd&1).
    int wadr[4];
#pragma unroll
    for (int ns = 0; ns < 4; ++ns)
        wadr[ns] = 80 * ln + 8 * ((2 * ns + (qd >> 1)) ^ sw) + 4 * (qd & 1);
    // P read addrs (A operand): row m=q=ln, keys kh*32 + qd*8..+7 -> chunk kh*4+qd, ^sw
    const bf16x8* rdp[2];
#pragma unroll
    for (int kh = 0; kh < 2; ++kh)
        rdp[kh] = (const bf16x8*)&psw[80 * ln + 8 * (((kh * 4 + qd)) ^ sw)];

    float lsum = 0.f;
    f32x4 oacc[2] = {};

    bf16x8 kf[4], vf[4];
#pragma unroll
    for (int ns = 0; ns < 4; ++ns)
        kf[ns] = *(const bf16x8*)&K[(kbase + ns * 16 + ln) * DK + qd * 8];
    vf[0] = *(const bf16x8*)&Vt[( 0 + ln) * NTOK + kbase +  0 + qd * 8];
    vf[1] = *(const bf16x8*)&Vt[( 0 + ln) * NTOK + kbase + 32 + qd * 8];
    vf[2] = *(const bf16x8*)&Vt[(16 + ln) * NTOK + kbase +  0 + qd * 8];
    vf[3] = *(const bf16x8*)&Vt[(16 + ln) * NTOK + kbase + 32 + qd * 8];

#pragma unroll
    for (int kt = 0; kt < 8; ++kt) {
        bf16x8 nkf[4], nvf[4];
        if (kt < 7) {
            int k1 = kbase + (kt + 1) * 64;
#pragma unroll
            for (int ns = 0; ns < 4; ++ns)
                nkf[ns] = *(const bf16x8*)&K[(k1 + ns * 16 + ln) * DK + qd * 8];
            nvf[0] = *(const bf16x8*)&Vt[( 0 + ln) * NTOK + k1 +  0 + qd * 8];
            nvf[1] = *(const bf16x8*)&Vt[( 0 + ln) * NTOK + k1 + 32 + qd * 8];
            nvf[2] = *(const bf16x8*)&Vt[(16 + ln) * NTOK + k1 +  0 + qd * 8];
            nvf[3] = *(const bf16x8*)&Vt[(16 + ln) * NTOK + k1 + 32 + qd * 8];
        }

        // S^T = K Q^T : lane: col q=ln, rows key = kt*64 + ns*16 + qd*4 + r
        f32x4 s[4];
        f32x4 z = {0.f, 0.f, 0.f, 0.f};
#pragma unroll
        for (int ns = 0; ns < 4; ++ns)
            s[ns] = __builtin_amdgcn_mfma_f32_16x16x32_bf16(kf[ns], qf, z, 0, 0, 0);

        // p = exp2(s) (log2e pre-folded); pack 2x bf16 (truncate) via v_perm; 4 ds_write_b64
#pragma unroll
        for (int ns = 0; ns < 4; ++ns) {
            float p0 = __builtin_amdgcn_exp2f(s[ns][0]);
            float p1 = __builtin_amdgcn_exp2f(s[ns][1]);
            float p2 = __builtin_amdgcn_exp2f(s[ns][2]);
            float p3 = __builtin_amdgcn_exp2f(s[ns][3]);
            lsum += (p0 + p1) + (p2 + p3);
            u32 dw0 = __builtin_amdgcn_perm(__float_as_uint(p1), __float_as_uint(p0), 0x07060302u);
            u32 dw1 = __builtin_amdgcn_perm(__float_as_uint(p3), __float_as_uint(p2), 0x07060302u);
            *(uint2*)&psw[wadr[ns]] = make_uint2(dw0, dw1);
        }

        // O += P V   (A = P from LDS, B = V^T fragments)
        bf16x8 pf0 = *rdp[0];
        bf16x8 pf1 = *rdp[1];
        oacc[0] = __builtin_amdgcn_mfma_f32_16x16x32_bf16(pf0, vf[0], oacc[0], 0, 0, 0);
        oacc[0] = __builtin_amdgcn_mfma_f32_16x16x32_bf16(pf1, vf[1], oacc[0], 0, 0, 0);
        oacc[1] = __builtin_amdgcn_mfma_f32_16x16x32_bf16(pf0, vf[2], oacc[1], 0, 0, 0);
        oacc[1] = __builtin_amdgcn_mfma_f32_16x16x32_bf16(pf1, vf[3], oacc[1], 0, 0, 0);

#pragma unroll
        for (int i = 0; i < 4; ++i) { kf[i] = nkf[i]; vf[i] = nvf[i]; }
    }

    // reduce l over quads (keys are split across quads and ns within the wave)
    lsum += __shfl_xor(lsum, 16, 64);
    lsum += __shfl_xor(lsum, 32, 64);

    // merge the two k-halves (no-max softmax: plain adds)
    if (khalf == 1) {
        xl[qsub][l] = lsum;
#pragma unroll
        for (int i = 0; i < 4; ++i) {
            xo[qsub][l][i] = oacc[0][i];
            xo[qsub][l][4 + i] = oacc[1][i];
        }
    }
    __syncthreads();
    if (khalf == 0) {
        lsum += xl[qsub][l];
#pragma unroll
        for (int i = 0; i < 4; ++i) {
            oacc[0][i] += xo[qsub][l][i];
            oacc[1][i] += xo[qsub][l][4 + i];
        }
        // linv for the 4 q-rows this lane's C-registers cover: q = qd*4 + r (held at lane qd*4+r)
        float linv[4];
#pragma unroll
        for (int r = 0; r < 4; ++r)
            linv[r] = 1.0f / __shfl(lsum, qd * 4 + r, 64);
#pragma unroll
        for (int ns = 0; ns < 2; ++ns) {
#pragma unroll
            for (int r = 0; r < 4; ++r) {
                int n_row = qp * 32 + qsub * 16 + qd * 4 + r;
                float v = oacc[ns][r] * linv[r];
                tmp[((size_t)b * NTOK + n_row) * DMODEL + h * DK + ns * 16 + ln] = f2b(v);
            }
        }
    }
}

// ---------------- Kernel 5: output projection + bias + residual (LDS-staged, fp32 out) ----------------
__global__ __launch_bounds__(256) void oproj(
    const u16* __restrict__ tmp, const u16* __restrict__ wb,
    const float* __restrict__ bo, const float* __restrict__ x,
    float* __restrict__ out) {
    int mt = blockIdx.x;
    int ot = blockIdx.y;
    int b = blockIdx.z;
    const u16* Wo = wb + 3 * 65536;

    __shared__ u16 As[64][40];
    __shared__ u16 Bs[64][40];
    int t = threadIdx.x;
    int w = t >> 6, l = t & 63;
    int lr = t >> 2;
    int lc = (t & 3) * 8;
    int qd = l >> 4, ln = l & 15;

    const u16* ab = tmp + ((size_t)b * NTOK + mt * 64) * DMODEL;
    f32x4 acc[4] = {};
    for (int kb = 0; kb < 8; ++kb) {
        *(uint4*)&As[lr][lc] = *(const uint4*)&ab[lr * DMODEL + kb * 32 + lc];
        *(uint4*)&Bs[lr][lc] = *(const uint4*)&Wo[(ot * 64 + lr) * DMODEL + kb * 32 + lc];
        __syncthreads();
        bf16x8 af = *(const bf16x8*)&As[w * 16 + ln][qd * 8];
#pragma unroll
        for (int ns = 0; ns < 4; ++ns) {
            bf16x8 bf = *(const bf16x8*)&Bs[ns * 16 + ln][qd * 8];
            acc[ns] = __builtin_amdgcn_mfma_f32_16x16x32_bf16(af, bf, acc[ns], 0, 0, 0);
        }
        __syncthreads();
    }
    const float* xb = x + (size_t)b * PER_B;
    float* ob = out + (size_t)b * PER_B;
#pragma unroll
    for (int ns = 0; ns < 4; ++ns) {
        int o = ot * 64 + ns * 16 + ln;
        float bias_f = bo[o];
#pragma unroll
        for (int r = 0; r < 4; ++r) {
            int n_row = mt * 64 + w * 16 + qd * 4 + r;
            size_t idx = (size_t)n_row * DMODEL + o;
            ob[idx] = acc[ns][r] + bias_f + xb[idx];
        }
    }
}

extern "C" void kernel_launch(void* const* d_in, const int* in_sizes, int n_in,
                              void* d_out, int out_size, void* d_ws, size_t ws_size,
                              hipStream_t stream) {
    const float* x  = (const float*)d_in[0];
    const float* Wq = (const float*)d_in[1];
    const float* bq = (const float*)d_in[2];
    const float* Wk = (const float*)d_in[3];
    const float* bk = (const float*)d_in[4];
    const float* Wv = (const float*)d_in[5];
    const float* bv = (const float*)d_in[6];
    const float* Wo = (const float*)d_in[7];
    const float* bo = (const float*)d_in[8];
    float* out = (float*)d_out;

    char* ws = (char*)d_ws;
    float* part = (float*)ws;                          // 1 KB
    u16* wb  = (u16*)(ws + 1024);                      // 512 KB
    u16* xn  = (u16*)(ws + 1024 + (512u << 10));       // 4 MB (reused as attn output tmp)
    u16* qws = (u16*)(ws + 1024 + (512u << 10) + (4u << 20));
    u16* kws = (u16*)(ws + 1024 + (512u << 10) + (8u << 20));
    u16* vws = (u16*)(ws + 1024 + (512u << 10) + (12u << 20));  // transposed [bh][dv][n]
    u16* tmp = xn;

    hipLaunchKernelGGL(prep, dim3(320), dim3(256), 0, stream, Wq, Wk, Wv, Wo, wb, x, part);
    hipLaunchKernelGGL(normT, dim3(32, 8, 8), dim3(32, 8), 0, stream, x, part, xn);
    hipLaunchKernelGGL(qkv_gemm, dim3(16, 12, 8), dim3(256), 0, stream,
                       xn, wb, bq, bk, bv, qws, kws, vws);
    hipLaunchKernelGGL(attn, dim3(64, 32), dim3(256), 0, stream, qws, kws, vws, tmp);
    hipLaunchKernelGGL(oproj, dim3(16, 4, 8), dim3(256), 0, stream, tmp, wb, bo, x, out);
}